// Round 6
// baseline (6660.008 us; speedup 1.0000x reference)
//
#include <hip/hip_runtime.h>
#include <hip/hip_bf16.h>
#include <stdint.h>

#define B_SZ 8192
#define T_SZ 24
#define H_SZ 1024
#define G4   4096   // 4*H

typedef __attribute__((ext_vector_type(8))) short bf16x8;
typedef __attribute__((ext_vector_type(4))) float f32x4;

// Gate-interleaved permutation: new row p -> old row.
__device__ __forceinline__ int perm_old(int p) {
    int gate = (p >> 4) & 3;
    int unit = ((p >> 6) << 4) | (p & 15);
    return gate * 1024 + unit;
}

__device__ __forceinline__ float fast_sigmoid(float x) {
    return 1.f / (1.f + __expf(-x));
}
__device__ __forceinline__ float fast_tanh(float x) {
    float ax = __builtin_fabsf(x);
    float e  = __expf(2.f * ax);          // inf for large ax -> r = 1
    float r  = 1.f - 2.f / (e + 1.f);
    return __builtin_copysignf(r, x);
}

// ---------------- prep kernels (run once per launch) ----------------
__global__ void k_prep_w1(const float* __restrict__ Whh1, __hip_bfloat16* __restrict__ dst) {
    int i = blockIdx.x * blockDim.x + threadIdx.x;   // over 4096*1024
    int p = i >> 10, k = i & 1023;
    dst[i] = __float2bfloat16(Whh1[(size_t)perm_old(p) * 1024 + k]);
}

__global__ void k_prep_w2(const float* __restrict__ Wih2, const float* __restrict__ Whh2,
                          __hip_bfloat16* __restrict__ dst) {
    int i = blockIdx.x * blockDim.x + threadIdx.x;   // over 4096*2048
    int p = i >> 11, k = i & 2047;
    int old = perm_old(p);
    float v = (k < 1024) ? Wih2[(size_t)old * 1024 + k] : Whh2[(size_t)old * 1024 + (k - 1024)];
    dst[i] = __float2bfloat16(v);
}

__global__ void k_prep_vec(const float* __restrict__ bih1, const float* __restrict__ bhh1,
                           const float* __restrict__ bih2, const float* __restrict__ bhh2,
                           const float* __restrict__ Wih1,
                           float* __restrict__ b1p, float* __restrict__ b2p,
                           float* __restrict__ w1p) {
    int p = blockIdx.x * blockDim.x + threadIdx.x;
    if (p >= G4) return;
    int old = perm_old(p);
    b1p[p] = bih1[old] + bhh1[old];
    b2p[p] = bih2[old] + bhh2[old];
    w1p[p] = Wih1[old];
}

__global__ void k_xT(const float* __restrict__ x, float* __restrict__ xT) {
    int i = blockIdx.x * blockDim.x + threadIdx.x;   // over B*T
    if (i >= B_SZ * T_SZ) return;
    int b = i / T_SZ, t = i % T_SZ;
    xT[t * B_SZ + b] = x[i];
}

__global__ void k_init_state(const float* __restrict__ h1_0, const float* __restrict__ c1_0,
                             const float* __restrict__ h2_0, const float* __restrict__ c2_0,
                             __hip_bfloat16* __restrict__ A2_0, __hip_bfloat16* __restrict__ A2_1,
                             float* __restrict__ c1, float* __restrict__ c2) {
    int i = blockIdx.x * blockDim.x + threadIdx.x;   // over B*H
    if (i >= B_SZ * H_SZ) return;
    int b = i >> 10, j = i & 1023;
    A2_1[(size_t)b * 2048 + j]        = __float2bfloat16(h1_0[i]);
    A2_0[(size_t)b * 2048 + 1024 + j] = __float2bfloat16(h2_0[i]);
    c1[i] = c1_0[i];
    c2[i] = c2_0[i];
}

// ---------------- fused GEMM + LSTM cell, 256x256, region-recycled pipeline ------
// 8 waves (2M x 4N), per-wave 128x64 C, BK=64, LDS 2-buf 128 KiB.
// Per K-tile: 4 quadrant phases. Region recycling invariant: every phase's
// lgkmcnt(0) sits BEFORE its end-barrier, so by that barrier all waves' LDS
// reads of this phase are COMPLETE -> the next phase may stage-overwrite the
// regions this phase read. Stage issues (2 global_load_lds each):
//   p2: u1[kt+2](A-mq0, read p1) + u3[kt+2](B-nq0, read p1)
//   p3: u4[kt+2](B-nq1, read p2)
//   p4: u2[kt+2](A-mq1, read p3)
// ONE counted wait per K-tile: p4-end vmcnt(8) (the 8 newest = tile kt+2's
// issues) => all of tile kt+1 landed before next p1. Tail: kt+2>=NK -> 0.
// mode: 0 = all blocks layer-2, 1 = dual (L2(t) + L1(t+1)), 2 = all layer-1.
#define BM 256
#define BN 256
#define BK 64

__global__ __launch_bounds__(512, 2)
void k_gemm_dual(const __hip_bfloat16* __restrict__ A,
                 const __hip_bfloat16* __restrict__ W2, const float* __restrict__ bias2,
                 float* __restrict__ c2p, __hip_bfloat16* __restrict__ hout2,
                 const __hip_bfloat16* __restrict__ W1, const float* __restrict__ bias1,
                 const float* __restrict__ wih1p, const float* __restrict__ xT, int t1,
                 float* __restrict__ c1p, __hip_bfloat16* __restrict__ hout1,
                 int mode) {
    __shared__ short As[2][BM][BK];   // 64 KiB
    __shared__ short Bs[2][BN][BK];   // 64 KiB
    const int tid  = threadIdx.x;
    const int lane = tid & 63;
    const int wid  = tid >> 6;        // 0..7

    // role split: groups of 8 blocks (one per XCD) alternate roles
    const int bid = blockIdx.x;
    int role, sub;
    if (mode == 1) { role = (bid >> 3) & 1; sub = ((bid >> 4) << 3) | (bid & 7); }
    else           { role = (mode == 2) ? 1 : 0; sub = bid; }

    const __hip_bfloat16* Bw;
    const float* biasp;
    const float* w1p;
    float* c;
    __hip_bfloat16* hout;
    int ldb, K;
    if (role == 0) { Bw = W2; ldb = 2048; K = 2048; biasp = bias2; w1p = nullptr; c = c2p; hout = hout2; }
    else           { Bw = W1; ldb = 1024; K = 1024; biasp = bias1; w1p = wih1p;  c = c1p; hout = hout1; }
    const int lda = 2048;

    // XCD slab mapping on sub-grid (512 blocks): xcd = sub&7 owns 16m x 4n slab,
    // within-slab m-fastest-over-8 -> ~8m x 4n concurrent group per XCD.
    const int xcd = sub & 7;
    const int i   = sub >> 3;                      // 0..63
    const int ml  = (i & 7) | ((i >> 5) << 3);     // 0..15
    const int nl  = (i >> 3) & 3;                  // 0..3
    const int m0  = ((xcd & 1) * 16 + ml) * BM;
    const int n0  = ((xcd >> 1) * 4 + nl) * BN;

    const int wm = wid >> 2;          // 0..1
    const int wn = wid & 3;           // 0..3
    const int fr = lane & 15;
    const int kg = lane >> 4;

    const __hip_bfloat16* Abase = A  + (size_t)m0 * lda;
    const __hip_bfloat16* Bbase = Bw + (size_t)n0 * ldb;

    f32x4 acc[8][4];
#pragma unroll
    for (int ii = 0; ii < 8; ++ii)
#pragma unroll
        for (int j = 0; j < 4; ++j) acc[ii][j] = (f32x4)0.f;

    // staging: one global_load_lds covers 8 LDS rows; source col pre-swizzled
    // (chunk ^= row&7) so linear LDS dest + same-XOR read = involution.
    auto stage8A = [&](int buf, int lr0, int kcol) {
        int lr = lr0 + (lane >> 3);
        int scol = (((lane & 7) ^ (lr & 7)) << 3);
        const __hip_bfloat16* gp = Abase + (size_t)lr * lda + kcol + scol;
        __builtin_amdgcn_global_load_lds(
            (const __attribute__((address_space(1))) void*)gp,
            (__attribute__((address_space(3))) void*)(&As[buf][lr0][0]), 16, 0, 0);
    };
    auto stage8B = [&](int buf, int lr0, int kcol) {
        int lr = lr0 + (lane >> 3);
        int scol = (((lane & 7) ^ (lr & 7)) << 3);
        const __hip_bfloat16* gp = Bbase + (size_t)lr * ldb + kcol + scol;
        __builtin_amdgcn_global_load_lds(
            (const __attribute__((address_space(1))) void*)gp,
            (__attribute__((address_space(3))) void*)(&Bs[buf][lr0][0]), 16, 0, 0);
    };
    auto stage_u1 = [&](int kt, int buf) {   // A rows (r%128)<64  (A-mq0)
#pragma unroll
        for (int j = 0; j < 2; ++j) {
            int rr0 = (wid * 2 + j) * 8;
            int lr0 = (rr0 < 64) ? rr0 : rr0 + 64;
            stage8A(buf, lr0, kt * BK);
        }
    };
    auto stage_u2 = [&](int kt, int buf) {   // A rows (r%128)>=64 (A-mq1)
#pragma unroll
        for (int j = 0; j < 2; ++j) {
            int rr0 = (wid * 2 + j) * 8;
            int lr0 = (rr0 < 64) ? rr0 + 64 : rr0 + 128;
            stage8A(buf, lr0, kt * BK);
        }
    };
    auto stage_u3 = [&](int kt, int buf) {   // B rows (r%64)<32   (B-nq0)
#pragma unroll
        for (int j = 0; j < 2; ++j) {
            int rr0 = (wid * 2 + j) * 8;
            int lr0 = ((rr0 >> 5) << 6) + (rr0 & 31);
            stage8B(buf, lr0, kt * BK);
        }
    };
    auto stage_u4 = [&](int kt, int buf) {   // B rows (r%64)>=32  (B-nq1)
#pragma unroll
        for (int j = 0; j < 2; ++j) {
            int rr0 = (wid * 2 + j) * 8;
            int lr0 = ((rr0 >> 5) << 6) + 32 + (rr0 & 31);
            stage8B(buf, lr0, kt * BK);
        }
    };

    // hoisted LDS read bases (element offsets into a [256][64] short tile)
    const int aoff = (wm * 128 + fr) * 64;         // + m*1024 + ck8[ks]
    const int boff = (wn * 64 + fr) * 64;          // + n*1024 + ck8[ks]
    const int ck8_0 = ((kg ^ (fr & 7)) << 3);
    const int ck8_1 = (((4 + kg) ^ (fr & 7)) << 3);
    const short* As0 = &As[0][0][0];
    const short* As1 = &As[1][0][0];
    const short* Bs0 = &Bs[0][0][0];
    const short* Bs1 = &Bs[1][0][0];

    const int NK = K >> 6;

    // ---- prologue: tile0 (u1,u3,u2,u4) then tile1 (u1,u3,u4,u2) ----
    stage_u1(0, 0); stage_u3(0, 0); stage_u2(0, 0); stage_u4(0, 0);
    stage_u1(1, 1); stage_u3(1, 1); stage_u4(1, 1); stage_u2(1, 1);
    asm volatile("s_waitcnt vmcnt(8)" ::: "memory");   // tile-0 landed
    __builtin_amdgcn_s_barrier();

    bf16x8 a0[4][2], a1[4][2], b0[2][2], b1[2][2];

    for (int kt = 0; kt < NK; ++kt) {
        const int buf = kt & 1;
        const short* as = buf ? As1 : As0;
        const short* bs = buf ? Bs1 : Bs0;

        // ---------- phase 1: quadrant (mq0, nq0), 12 ds_reads, no stage ----------
#pragma unroll
        for (int m = 0; m < 4; ++m) {
            a0[m][0] = *(const bf16x8*)(as + aoff + m * 1024 + ck8_0);
            a0[m][1] = *(const bf16x8*)(as + aoff + m * 1024 + ck8_1);
        }
#pragma unroll
        for (int n = 0; n < 2; ++n) {
            b0[n][0] = *(const bf16x8*)(bs + boff + n * 1024 + ck8_0);
            b0[n][1] = *(const bf16x8*)(bs + boff + n * 1024 + ck8_1);
        }
        asm volatile("s_waitcnt lgkmcnt(8)" ::: "memory");
        __builtin_amdgcn_s_barrier();
        asm volatile("s_waitcnt lgkmcnt(0)" ::: "memory");
        __builtin_amdgcn_s_setprio(1);
#pragma unroll
        for (int ks = 0; ks < 2; ++ks)
#pragma unroll
            for (int m = 0; m < 4; ++m)
#pragma unroll
                for (int n = 0; n < 2; ++n)
                    acc[m][n] = __builtin_amdgcn_mfma_f32_16x16x32_bf16(a0[m][ks], b0[n][ks], acc[m][n], 0, 0, 0);
        __builtin_amdgcn_s_setprio(0);
        __builtin_amdgcn_s_barrier();

        // ---------- phase 2: quadrant (mq0, nq1), 4 ds_reads, stage u1,u3[kt+2] ----------
#pragma unroll
        for (int n = 0; n < 2; ++n) {
            b1[n][0] = *(const bf16x8*)(bs + boff + (2 + n) * 1024 + ck8_0);
            b1[n][1] = *(const bf16x8*)(bs + boff + (2 + n) * 1024 + ck8_1);
        }
        if (kt + 2 < NK) { stage_u1(kt + 2, buf); stage_u3(kt + 2, buf); }
        __builtin_amdgcn_s_barrier();
        asm volatile("s_waitcnt lgkmcnt(0)" ::: "memory");
        __builtin_amdgcn_s_setprio(1);
#pragma unroll
        for (int ks = 0; ks < 2; ++ks)
#pragma unroll
            for (int m = 0; m < 4; ++m)
#pragma unroll
                for (int n = 0; n < 2; ++n)
                    acc[m][2 + n] = __builtin_amdgcn_mfma_f32_16x16x32_bf16(a0[m][ks], b1[n][ks], acc[m][2 + n], 0, 0, 0);
        __builtin_amdgcn_s_setprio(0);
        __builtin_amdgcn_s_barrier();

        // ---------- phase 3: quadrant (mq1, nq0), 8 ds_reads, stage u4[kt+2] ----------
#pragma unroll
        for (int m = 0; m < 4; ++m) {
            a1[m][0] = *(const bf16x8*)(as + aoff + (4 + m) * 1024 + ck8_0);
            a1[m][1] = *(const bf16x8*)(as + aoff + (4 + m) * 1024 + ck8_1);
        }
        if (kt + 2 < NK) stage_u4(kt + 2, buf);
        __builtin_amdgcn_s_barrier();
        asm volatile("s_waitcnt lgkmcnt(0)" ::: "memory");
        __builtin_amdgcn_s_setprio(1);
#pragma unroll
        for (int ks = 0; ks < 2; ++ks)
#pragma unroll
            for (int m = 0; m < 4; ++m)
#pragma unroll
                for (int n = 0; n < 2; ++n)
                    acc[4 + m][n] = __builtin_amdgcn_mfma_f32_16x16x32_bf16(a1[m][ks], b0[n][ks], acc[4 + m][n], 0, 0, 0);
        __builtin_amdgcn_s_setprio(0);
        __builtin_amdgcn_s_barrier();

        // ---------- phase 4: quadrant (mq1, nq1), 0 ds_reads, stage u2[kt+2] ----------
        if (kt + 2 < NK) stage_u2(kt + 2, buf);
        __builtin_amdgcn_s_barrier();
        __builtin_amdgcn_s_setprio(1);
#pragma unroll
        for (int ks = 0; ks < 2; ++ks)
#pragma unroll
            for (int m = 0; m < 4; ++m)
#pragma unroll
                for (int n = 0; n < 2; ++n)
                    acc[4 + m][2 + n] = __builtin_amdgcn_mfma_f32_16x16x32_bf16(a1[m][ks], b1[n][ks], acc[4 + m][2 + n], 0, 0, 0);
        __builtin_amdgcn_s_setprio(0);
        if (kt + 2 < NK)      asm volatile("s_waitcnt vmcnt(8)" ::: "memory");
        else if (kt + 1 < NK) asm volatile("s_waitcnt vmcnt(0)" ::: "memory");
        __builtin_amdgcn_s_barrier();
    }

    // ---- fused cell epilogue ----
    float biasv[4], xwv[4];
#pragma unroll
    for (int n = 0; n < 4; ++n) {
        int col = n0 + wn * 64 + n * 16 + fr;
        biasv[n] = biasp[col];
        xwv[n] = (w1p != nullptr) ? w1p[col] : 0.f;
    }
    const int u = ((n0 >> 6) + wn) * 16 + fr;   // global unit index 0..1023

#pragma unroll
    for (int m = 0; m < 8; ++m) {
        int rbase = m0 + wm * 128 + m * 16 + (lane >> 4) * 4;
#pragma unroll
        for (int j = 0; j < 4; ++j) {
            int b = rbase + j;
            float gi = acc[m][0][j] + biasv[0];
            float gf = acc[m][1][j] + biasv[1];
            float gg = acc[m][2][j] + biasv[2];
            float go = acc[m][3][j] + biasv[3];
            if (w1p != nullptr) {
                float xv = xT[t1 * B_SZ + b];
                gi += xv * xwv[0];
                gf += xv * xwv[1];
                gg += xv * xwv[2];
                go += xv * xwv[3];
            }
            float si = fast_sigmoid(gi);
            float sf = fast_sigmoid(gf);
            float so = fast_sigmoid(go);
            float tg = fast_tanh(gg);
            size_t ci = (size_t)b * H_SZ + u;
            float cn = sf * c[ci] + si * tg;
            c[ci] = cn;
            hout[(size_t)b * 2048 + u] = __float2bfloat16(so * fast_tanh(cn));
        }
    }
}

// ---------------- output projection ----------------
__global__ __launch_bounds__(256)
void k_out(const __hip_bfloat16* __restrict__ h2base, const float* __restrict__ Wout,
           const float* __restrict__ bout, float* __restrict__ out) {
    int gw   = (blockIdx.x * blockDim.x + threadIdx.x) >> 6;
    int lane = threadIdx.x & 63;
    if (gw >= B_SZ) return;
    const __hip_bfloat16* h = h2base + (size_t)gw * 2048;
    float a0 = 0.f, a1 = 0.f;
#pragma unroll
    for (int k = lane; k < 1024; k += 64) {
        float hv = __bfloat162float(h[k]);
        a0 += hv * Wout[k];
        a1 += hv * Wout[1024 + k];
    }
    for (int off = 32; off; off >>= 1) {
        a0 += __shfl_down(a0, off);
        a1 += __shfl_down(a1, off);
    }
    if (lane == 0) {
        out[gw * 2 + 0] = a0 + bout[0];
        out[gw * 2 + 1] = a1 + bout[1];
    }
}

extern "C" void kernel_launch(void* const* d_in, const int* in_sizes, int n_in,
                              void* d_out, int out_size, void* d_ws, size_t ws_size,
                              hipStream_t stream) {
    const float* x    = (const float*)d_in[0];
    const float* h1_0 = (const float*)d_in[1];
    const float* c1_0 = (const float*)d_in[2];
    const float* h2_0 = (const float*)d_in[3];
    const float* c2_0 = (const float*)d_in[4];
    const float* Wih1 = (const float*)d_in[5];
    const float* Whh1 = (const float*)d_in[6];
    const float* bih1 = (const float*)d_in[7];
    const float* bhh1 = (const float*)d_in[8];
    const float* Wih2 = (const float*)d_in[9];
    const float* Whh2 = (const float*)d_in[10];
    const float* bih2 = (const float*)d_in[11];
    const float* bhh2 = (const float*)d_in[12];
    const float* Wout = (const float*)d_in[13];
    const float* bout = (const float*)d_in[14];
    float* out = (float*)d_out;
    (void)in_sizes; (void)n_in; (void)out_size; (void)ws_size;

    uint8_t* ws = (uint8_t*)d_ws;
    size_t off = 0;
    auto alloc = [&](size_t bytes) { void* p = ws + off; off += (bytes + 255) & ~(size_t)255; return p; };
    __hip_bfloat16* A2_0  = (__hip_bfloat16*)alloc((size_t)B_SZ * 2048 * 2);
    __hip_bfloat16* A2_1  = (__hip_bfloat16*)alloc((size_t)B_SZ * 2048 * 2);
    float*          c1    = (float*)alloc((size_t)B_SZ * H_SZ * 4);
    float*          c2    = (float*)alloc((size_t)B_SZ * H_SZ * 4);
    __hip_bfloat16* Whh1p = (__hip_bfloat16*)alloc((size_t)G4 * H_SZ * 2);
    __hip_bfloat16* Wcat2p= (__hip_bfloat16*)alloc((size_t)G4 * 2048 * 2);
    float*          bias1p= (float*)alloc(G4 * 4);
    float*          bias2p= (float*)alloc(G4 * 4);
    float*          wih1p = (float*)alloc(G4 * 4);
    float*          xT    = (float*)alloc((size_t)T_SZ * B_SZ * 4);

    __hip_bfloat16* A2[2] = { A2_0, A2_1 };

    k_prep_w1<<<(G4 * H_SZ + 255) / 256, 256, 0, stream>>>(Whh1, Whh1p);
    k_prep_w2<<<(G4 * 2048 + 255) / 256, 256, 0, stream>>>(Wih2, Whh2, Wcat2p);
    k_prep_vec<<<(G4 + 255) / 256, 256, 0, stream>>>(bih1, bhh1, bih2, bhh2, Wih1,
                                                     bias1p, bias2p, wih1p);
    k_xT<<<(B_SZ * T_SZ + 255) / 256, 256, 0, stream>>>(x, xT);
    k_init_state<<<(B_SZ * H_SZ + 255) / 256, 256, 0, stream>>>(h1_0, c1_0, h2_0, c2_0,
                                                                A2_0, A2_1, c1, c2);

    // L1(0): all blocks layer-1. A = P_{-1} = A2[1]; h1_0 -> A2[0] first half.
    k_gemm_dual<<<512, 512, 0, stream>>>(
        (const __hip_bfloat16*)A2_1,
        Wcat2p, bias2p, c2, A2_0 + 1024,             // unused (role L2 absent)
        Whh1p, bias1p, wih1p, xT, 0, c1, A2_0,
        2);

    // merged: L2(t) || L1(t+1), t = 0..22
    for (int t = 0; t < 23; ++t) {
        __hip_bfloat16* Pt = A2[t & 1];
        __hip_bfloat16* Pn = A2[(t + 1) & 1];
        k_gemm_dual<<<1024, 512, 0, stream>>>(
            (const __hip_bfloat16*)Pt,
            Wcat2p, bias2p, c2, Pn + 1024,
            Whh1p, bias1p, wih1p, xT, t + 1, c1, Pn,
            1);
    }

    // L2(23): all blocks layer-2. A = P_23 = A2[1]; h2_23 -> A2[0] second half.
    k_gemm_dual<<<512, 512, 0, stream>>>(
        (const __hip_bfloat16*)A2_1,
        Wcat2p, bias2p, c2, A2_0 + 1024,
        Whh1p, bias1p, wih1p, xT, 0, c1, A2_0,      // L1 params unused
        0);

    k_out<<<(B_SZ * 64 + 255) / 256, 256, 0, stream>>>(A2_0 + 1024, Wout, bout, out);
}

// Round 7
// 5495.543 us; speedup vs baseline: 1.2119x; 1.2119x over previous
//
#include <hip/hip_runtime.h>
#include <hip/hip_bf16.h>
#include <stdint.h>

#define B_SZ 8192
#define T_SZ 24
#define H_SZ 1024
#define G4   4096   // 4*H

typedef __attribute__((ext_vector_type(8))) short bf16x8;
typedef __attribute__((ext_vector_type(4))) float f32x4;

// Gate-interleaved permutation: new row p -> old row.
__device__ __forceinline__ int perm_old(int p) {
    int gate = (p >> 4) & 3;
    int unit = ((p >> 6) << 4) | (p & 15);
    return gate * 1024 + unit;
}

__device__ __forceinline__ float fast_sigmoid(float x) {
    return 1.f / (1.f + __expf(-x));
}
__device__ __forceinline__ float fast_tanh(float x) {
    float ax = __builtin_fabsf(x);
    float e  = __expf(2.f * ax);          // inf for large ax -> r = 1
    float r  = 1.f - 2.f / (e + 1.f);
    return __builtin_copysignf(r, x);
}

// ---------------- prep kernels (run once per launch) ----------------
__global__ void k_prep_w1(const float* __restrict__ Whh1, __hip_bfloat16* __restrict__ dst) {
    int i = blockIdx.x * blockDim.x + threadIdx.x;   // over 4096*1024
    int p = i >> 10, k = i & 1023;
    dst[i] = __float2bfloat16(Whh1[(size_t)perm_old(p) * 1024 + k]);
}

__global__ void k_prep_w2(const float* __restrict__ Wih2, const float* __restrict__ Whh2,
                          __hip_bfloat16* __restrict__ dst) {
    int i = blockIdx.x * blockDim.x + threadIdx.x;   // over 4096*2048
    int p = i >> 11, k = i & 2047;
    int old = perm_old(p);
    float v = (k < 1024) ? Wih2[(size_t)old * 1024 + k] : Whh2[(size_t)old * 1024 + (k - 1024)];
    dst[i] = __float2bfloat16(v);
}

__global__ void k_prep_vec(const float* __restrict__ bih1, const float* __restrict__ bhh1,
                           const float* __restrict__ bih2, const float* __restrict__ bhh2,
                           const float* __restrict__ Wih1,
                           float* __restrict__ b1p, float* __restrict__ b2p,
                           float* __restrict__ w1p) {
    int p = blockIdx.x * blockDim.x + threadIdx.x;
    if (p >= G4) return;
    int old = perm_old(p);
    b1p[p] = bih1[old] + bhh1[old];
    b2p[p] = bih2[old] + bhh2[old];
    w1p[p] = Wih1[old];
}

__global__ void k_xT(const float* __restrict__ x, float* __restrict__ xT) {
    int i = blockIdx.x * blockDim.x + threadIdx.x;   // over B*T
    if (i >= B_SZ * T_SZ) return;
    int b = i / T_SZ, t = i % T_SZ;
    xT[t * B_SZ + b] = x[i];
}

__global__ void k_init_state(const float* __restrict__ h1_0, const float* __restrict__ c1_0,
                             const float* __restrict__ h2_0, const float* __restrict__ c2_0,
                             __hip_bfloat16* __restrict__ A2_0, __hip_bfloat16* __restrict__ A2_1,
                             float* __restrict__ c1, float* __restrict__ c2) {
    int i = blockIdx.x * blockDim.x + threadIdx.x;   // over B*H
    if (i >= B_SZ * H_SZ) return;
    int b = i >> 10, j = i & 1023;
    A2_1[(size_t)b * 2048 + j]        = __float2bfloat16(h1_0[i]);
    A2_0[(size_t)b * 2048 + 1024 + j] = __float2bfloat16(h2_0[i]);
    c1[i] = c1_0[i];
    c2[i] = c2_0[i];
}

// ---------------- fused GEMM + LSTM cell, 256x256, m201-faithful schedule --------
// 8 waves (2M x 4N), per-wave 128x64 C, BK=64, LDS 2-buf 128 KiB.
// 4 quadrant phases per K-tile, each:
//   {ds_read subtile ; issue stage unit(s) ; [lgkmcnt(8) if 12 reads] ; barrier ;
//    lgkmcnt(0) ; setprio(1) ; 16 MFMA ; setprio(0) ; [p4 only: counted vmcnt] ; barrier}
// Region-recycling invariant: every phase's reads complete before its END
// barrier (lgkmcnt(0) precedes the MFMA), so the NEXT phase may stage into the
// regions this phase read. Stage issues (per thread loads):
//   p2: u1[kt+2](A-a0 rows, read p1) + u3[kt+2](B-b0 rows, read p1)   [4 loads]
//   p3: u4[kt+2](B-b1 rows, read p2)                                   [2 loads]
//   p4: u2[kt+2](A-a1 rows, read p3)                                   [2 loads]
// ONE counted wait per K-tile: p4-end vmcnt(8) (8 newest = tile kt+2's issues)
// => all of tile kt+1 has landed before its p1. Tail: kt+2>=NK -> vmcnt(0) once.
#define BM 256
#define BN 256
#define BK 64

template<int LAYER>
__global__ __launch_bounds__(512, 2)
void k_gemm_cell(const __hip_bfloat16* __restrict__ A, int lda,
                 const __hip_bfloat16* __restrict__ Bw, int ldb, int K,
                 const float* __restrict__ biasp, const float* __restrict__ wih1p,
                 const float* __restrict__ xT, int t,
                 float* __restrict__ c, __hip_bfloat16* __restrict__ hout) {
    __shared__ short As[2][BM][BK];   // 64 KiB
    __shared__ short Bs[2][BN][BK];   // 64 KiB
    const int tid  = threadIdx.x;
    const int lane = tid & 63;
    const int wid  = tid >> 6;        // 0..7

    // XCD slab mapping (512 blocks): xcd = bid&7 owns a 16m x 4n slab,
    // within-slab m-fastest-over-8 -> ~8m x 4n concurrent group per XCD.
    const int bid = blockIdx.x;
    const int xcd = bid & 7;
    const int i   = bid >> 3;                      // 0..63
    const int ml  = (i & 7) | ((i >> 5) << 3);     // 0..15
    const int nl  = (i >> 3) & 3;                  // 0..3
    const int m0  = ((xcd & 1) * 16 + ml) * BM;
    const int n0  = ((xcd >> 1) * 4 + nl) * BN;

    const int wm = wid >> 2;          // 0..1
    const int wn = wid & 3;           // 0..3
    const int fr = lane & 15;
    const int kg = lane >> 4;

    const __hip_bfloat16* Abase = A  + (size_t)m0 * lda;
    const __hip_bfloat16* Bbase = Bw + (size_t)n0 * ldb;

    f32x4 acc[8][4];
#pragma unroll
    for (int ii = 0; ii < 8; ++ii)
#pragma unroll
        for (int j = 0; j < 4; ++j) acc[ii][j] = (f32x4)0.f;

    // staging: one global_load_lds covers 8 LDS rows; source col pre-swizzled
    // (chunk ^= row&7) so linear LDS dest + same-XOR read = involution (rule #21).
    auto stage8A = [&](int buf, int lr0, int kcol) {
        int lr = lr0 + (lane >> 3);
        int scol = (((lane & 7) ^ (lr & 7)) << 3);
        const __hip_bfloat16* gp = Abase + (size_t)lr * lda + kcol + scol;
        __builtin_amdgcn_global_load_lds(
            (const __attribute__((address_space(1))) void*)gp,
            (__attribute__((address_space(3))) void*)(&As[buf][lr0][0]), 16, 0, 0);
    };
    auto stage8B = [&](int buf, int lr0, int kcol) {
        int lr = lr0 + (lane >> 3);
        int scol = (((lane & 7) ^ (lr & 7)) << 3);
        const __hip_bfloat16* gp = Bbase + (size_t)lr * ldb + kcol + scol;
        __builtin_amdgcn_global_load_lds(
            (const __attribute__((address_space(1))) void*)gp,
            (__attribute__((address_space(3))) void*)(&Bs[buf][lr0][0]), 16, 0, 0);
    };
    auto stage_u1 = [&](int kt, int buf) {   // A rows (r%128)<64  (a0 rows)
#pragma unroll
        for (int j = 0; j < 2; ++j) {
            int rr0 = (wid * 2 + j) * 8;
            int lr0 = (rr0 < 64) ? rr0 : rr0 + 64;
            stage8A(buf, lr0, kt * BK);
        }
    };
    auto stage_u2 = [&](int kt, int buf) {   // A rows (r%128)>=64 (a1 rows)
#pragma unroll
        for (int j = 0; j < 2; ++j) {
            int rr0 = (wid * 2 + j) * 8;
            int lr0 = (rr0 < 64) ? rr0 + 64 : rr0 + 128;
            stage8A(buf, lr0, kt * BK);
        }
    };
    auto stage_u3 = [&](int kt, int buf) {   // B rows (r%64)<32   (b0 rows)
#pragma unroll
        for (int j = 0; j < 2; ++j) {
            int rr0 = (wid * 2 + j) * 8;
            int lr0 = ((rr0 >> 5) << 6) + (rr0 & 31);
            stage8B(buf, lr0, kt * BK);
        }
    };
    auto stage_u4 = [&](int kt, int buf) {   // B rows (r%64)>=32  (b1 rows)
#pragma unroll
        for (int j = 0; j < 2; ++j) {
            int rr0 = (wid * 2 + j) * 8;
            int lr0 = ((rr0 >> 5) << 6) + 32 + (rr0 & 31);
            stage8B(buf, lr0, kt * BK);
        }
    };

    // hoisted LDS read bases (element offsets into a [256][64] short tile)
    const int aoff = (wm * 128 + fr) * 64;         // + m*1024 + ck8[ks]
    const int boff = (wn * 64 + fr) * 64;          // + n*1024 + ck8[ks]
    const int ck8_0 = ((kg ^ (fr & 7)) << 3);
    const int ck8_1 = (((4 + kg) ^ (fr & 7)) << 3);
    const short* As0 = &As[0][0][0];
    const short* As1 = &As[1][0][0];
    const short* Bs0 = &Bs[0][0][0];
    const short* Bs1 = &Bs[1][0][0];

    const int NK = K >> 6;

    // ---- prologue: tile0 (u1,u3,u2,u4) then tile1 (u1,u3,u4,u2) = 16 loads ----
    stage_u1(0, 0); stage_u3(0, 0); stage_u2(0, 0); stage_u4(0, 0);
    stage_u1(1, 1); stage_u3(1, 1); stage_u4(1, 1); stage_u2(1, 1);
    asm volatile("s_waitcnt vmcnt(8)" ::: "memory");   // tile-0 landed
    __builtin_amdgcn_s_barrier();

    bf16x8 a0[4][2], a1[4][2], b0[2][2], b1[2][2];

    for (int kt = 0; kt < NK; ++kt) {
        const int buf = kt & 1;
        const short* as = buf ? As1 : As0;
        const short* bs = buf ? Bs1 : Bs0;

        // ---------- phase 1: quadrant (mq0, nq0), 12 ds_reads, no stage ----------
#pragma unroll
        for (int m = 0; m < 4; ++m) {
            a0[m][0] = *(const bf16x8*)(as + aoff + m * 1024 + ck8_0);
            a0[m][1] = *(const bf16x8*)(as + aoff + m * 1024 + ck8_1);
        }
#pragma unroll
        for (int n = 0; n < 2; ++n) {
            b0[n][0] = *(const bf16x8*)(bs + boff + n * 1024 + ck8_0);
            b0[n][1] = *(const bf16x8*)(bs + boff + n * 1024 + ck8_1);
        }
        asm volatile("s_waitcnt lgkmcnt(8)" ::: "memory");
        __builtin_amdgcn_s_barrier();
        asm volatile("s_waitcnt lgkmcnt(0)" ::: "memory");
        __builtin_amdgcn_s_setprio(1);
#pragma unroll
        for (int ks = 0; ks < 2; ++ks)
#pragma unroll
            for (int m = 0; m < 4; ++m)
#pragma unroll
                for (int n = 0; n < 2; ++n)
                    acc[m][n] = __builtin_amdgcn_mfma_f32_16x16x32_bf16(a0[m][ks], b0[n][ks], acc[m][n], 0, 0, 0);
        __builtin_amdgcn_s_setprio(0);
        __builtin_amdgcn_s_barrier();

        // ---------- phase 2: quadrant (mq0, nq1), 4 ds_reads, stage u1,u3[kt+2] ----------
#pragma unroll
        for (int n = 0; n < 2; ++n) {
            b1[n][0] = *(const bf16x8*)(bs + boff + (2 + n) * 1024 + ck8_0);
            b1[n][1] = *(const bf16x8*)(bs + boff + (2 + n) * 1024 + ck8_1);
        }
        if (kt + 2 < NK) { stage_u1(kt + 2, buf); stage_u3(kt + 2, buf); }
        __builtin_amdgcn_s_barrier();
        asm volatile("s_waitcnt lgkmcnt(0)" ::: "memory");
        __builtin_amdgcn_s_setprio(1);
#pragma unroll
        for (int ks = 0; ks < 2; ++ks)
#pragma unroll
            for (int m = 0; m < 4; ++m)
#pragma unroll
                for (int n = 0; n < 2; ++n)
                    acc[m][2 + n] = __builtin_amdgcn_mfma_f32_16x16x32_bf16(a0[m][ks], b1[n][ks], acc[m][2 + n], 0, 0, 0);
        __builtin_amdgcn_s_setprio(0);
        __builtin_amdgcn_s_barrier();

        // ---------- phase 3: quadrant (mq1, nq0), 8 ds_reads, stage u4[kt+2] ----------
#pragma unroll
        for (int m = 0; m < 4; ++m) {
            a1[m][0] = *(const bf16x8*)(as + aoff + (4 + m) * 1024 + ck8_0);
            a1[m][1] = *(const bf16x8*)(as + aoff + (4 + m) * 1024 + ck8_1);
        }
        if (kt + 2 < NK) stage_u4(kt + 2, buf);
        __builtin_amdgcn_s_barrier();
        asm volatile("s_waitcnt lgkmcnt(0)" ::: "memory");
        __builtin_amdgcn_s_setprio(1);
#pragma unroll
        for (int ks = 0; ks < 2; ++ks)
#pragma unroll
            for (int m = 0; m < 4; ++m)
#pragma unroll
                for (int n = 0; n < 2; ++n)
                    acc[4 + m][n] = __builtin_amdgcn_mfma_f32_16x16x32_bf16(a1[m][ks], b0[n][ks], acc[4 + m][n], 0, 0, 0);
        __builtin_amdgcn_s_setprio(0);
        __builtin_amdgcn_s_barrier();

        // ---------- phase 4: quadrant (mq1, nq1), 0 ds_reads, stage u2[kt+2] ----------
        if (kt + 2 < NK) stage_u2(kt + 2, buf);
        __builtin_amdgcn_s_barrier();
        __builtin_amdgcn_s_setprio(1);
#pragma unroll
        for (int ks = 0; ks < 2; ++ks)
#pragma unroll
            for (int m = 0; m < 4; ++m)
#pragma unroll
                for (int n = 0; n < 2; ++n)
                    acc[4 + m][2 + n] = __builtin_amdgcn_mfma_f32_16x16x32_bf16(a1[m][ks], b1[n][ks], acc[4 + m][2 + n], 0, 0, 0);
        __builtin_amdgcn_s_setprio(0);
        if (kt + 2 < NK)      asm volatile("s_waitcnt vmcnt(8)" ::: "memory");
        else if (kt + 1 < NK) asm volatile("s_waitcnt vmcnt(0)" ::: "memory");
        __builtin_amdgcn_s_barrier();
    }

    // ---- fused cell epilogue ----
    float biasv[4], xwv[4];
#pragma unroll
    for (int n = 0; n < 4; ++n) {
        int col = n0 + wn * 64 + n * 16 + fr;
        biasv[n] = biasp[col];
        if (LAYER == 1) xwv[n] = wih1p[col];
    }
    const int u = ((n0 >> 6) + wn) * 16 + fr;   // global unit index 0..1023

#pragma unroll
    for (int m = 0; m < 8; ++m) {
        int rbase = m0 + wm * 128 + m * 16 + (lane >> 4) * 4;
#pragma unroll
        for (int j = 0; j < 4; ++j) {
            int b = rbase + j;
            float gi = acc[m][0][j] + biasv[0];
            float gf = acc[m][1][j] + biasv[1];
            float gg = acc[m][2][j] + biasv[2];
            float go = acc[m][3][j] + biasv[3];
            if (LAYER == 1) {
                float xv = xT[t * B_SZ + b];
                gi += xv * xwv[0];
                gf += xv * xwv[1];
                gg += xv * xwv[2];
                go += xv * xwv[3];
            }
            float si = fast_sigmoid(gi);
            float sf = fast_sigmoid(gf);
            float so = fast_sigmoid(go);
            float tg = fast_tanh(gg);
            size_t ci = (size_t)b * H_SZ + u;
            float cn = sf * c[ci] + si * tg;
            c[ci] = cn;
            hout[(size_t)b * 2048 + u] = __float2bfloat16(so * fast_tanh(cn));
        }
    }
}

// ---------------- output projection ----------------
__global__ __launch_bounds__(256)
void k_out(const __hip_bfloat16* __restrict__ h2base, const float* __restrict__ Wout,
           const float* __restrict__ bout, float* __restrict__ out) {
    int gw   = (blockIdx.x * blockDim.x + threadIdx.x) >> 6;
    int lane = threadIdx.x & 63;
    if (gw >= B_SZ) return;
    const __hip_bfloat16* h = h2base + (size_t)gw * 2048;
    float a0 = 0.f, a1 = 0.f;
#pragma unroll
    for (int k = lane; k < 1024; k += 64) {
        float hv = __bfloat162float(h[k]);
        a0 += hv * Wout[k];
        a1 += hv * Wout[1024 + k];
    }
    for (int off = 32; off; off >>= 1) {
        a0 += __shfl_down(a0, off);
        a1 += __shfl_down(a1, off);
    }
    if (lane == 0) {
        out[gw * 2 + 0] = a0 + bout[0];
        out[gw * 2 + 1] = a1 + bout[1];
    }
}

extern "C" void kernel_launch(void* const* d_in, const int* in_sizes, int n_in,
                              void* d_out, int out_size, void* d_ws, size_t ws_size,
                              hipStream_t stream) {
    const float* x    = (const float*)d_in[0];
    const float* h1_0 = (const float*)d_in[1];
    const float* c1_0 = (const float*)d_in[2];
    const float* h2_0 = (const float*)d_in[3];
    const float* c2_0 = (const float*)d_in[4];
    const float* Wih1 = (const float*)d_in[5];
    const float* Whh1 = (const float*)d_in[6];
    const float* bih1 = (const float*)d_in[7];
    const float* bhh1 = (const float*)d_in[8];
    const float* Wih2 = (const float*)d_in[9];
    const float* Whh2 = (const float*)d_in[10];
    const float* bih2 = (const float*)d_in[11];
    const float* bhh2 = (const float*)d_in[12];
    const float* Wout = (const float*)d_in[13];
    const float* bout = (const float*)d_in[14];
    float* out = (float*)d_out;
    (void)in_sizes; (void)n_in; (void)out_size; (void)ws_size;

    uint8_t* ws = (uint8_t*)d_ws;
    size_t off = 0;
    auto alloc = [&](size_t bytes) { void* p = ws + off; off += (bytes + 255) & ~(size_t)255; return p; };
    __hip_bfloat16* A2_0  = (__hip_bfloat16*)alloc((size_t)B_SZ * 2048 * 2);
    __hip_bfloat16* A2_1  = (__hip_bfloat16*)alloc((size_t)B_SZ * 2048 * 2);
    float*          c1    = (float*)alloc((size_t)B_SZ * H_SZ * 4);
    float*          c2    = (float*)alloc((size_t)B_SZ * H_SZ * 4);
    __hip_bfloat16* Whh1p = (__hip_bfloat16*)alloc((size_t)G4 * H_SZ * 2);
    __hip_bfloat16* Wcat2p= (__hip_bfloat16*)alloc((size_t)G4 * 2048 * 2);
    float*          bias1p= (float*)alloc(G4 * 4);
    float*          bias2p= (float*)alloc(G4 * 4);
    float*          wih1p = (float*)alloc(G4 * 4);
    float*          xT    = (float*)alloc((size_t)T_SZ * B_SZ * 4);

    __hip_bfloat16* A2[2] = { A2_0, A2_1 };

    k_prep_w1<<<(G4 * H_SZ + 255) / 256, 256, 0, stream>>>(Whh1, Whh1p);
    k_prep_w2<<<(G4 * 2048 + 255) / 256, 256, 0, stream>>>(Wih2, Whh2, Wcat2p);
    k_prep_vec<<<(G4 + 255) / 256, 256, 0, stream>>>(bih1, bhh1, bih2, bhh2, Wih1,
                                                     bias1p, bias2p, wih1p);
    k_xT<<<(B_SZ * T_SZ + 255) / 256, 256, 0, stream>>>(x, xT);
    k_init_state<<<(B_SZ * H_SZ + 255) / 256, 256, 0, stream>>>(h1_0, c1_0, h2_0, c2_0,
                                                                A2_0, A2_1, c1, c2);

    const int gemm_blocks = (B_SZ / BM) * (G4 / BN);   // 512

    for (int t = 0; t < T_SZ; ++t) {
        __hip_bfloat16* Pprev = A2[(t + 1) & 1];   // P_{t-1}
        __hip_bfloat16* Pt    = A2[t & 1];         // P_t
        // layer 1: reads h1_{t-1} (Pprev first half), writes h1_t -> Pt first half
        k_gemm_cell<1><<<gemm_blocks, 512, 0, stream>>>(
            (const __hip_bfloat16*)Pprev, 2048, Whh1p, 1024, 1024,
            bias1p, wih1p, xT, t, c1, Pt);
        // layer 2: reads [h1_t | h2_{t-1}] = Pt, writes h2_t -> P_{t+1} second half
        k_gemm_cell<2><<<gemm_blocks, 512, 0, stream>>>(
            (const __hip_bfloat16*)Pt, 2048, Wcat2p, 2048, 2048,
            bias2p, nullptr, nullptr, 0, c2, A2[(t + 1) & 1] + 1024);
    }
    // final h2 is in P_24 = A2[0] second half (T=24 even)
    k_out<<<(B_SZ * 64 + 255) / 256, 256, 0, stream>>>(A2_0 + 1024, Wout, bout, out);
}